// Round 3
// baseline (613.126 us; speedup 1.0000x reference)
//
#include <hip/hip_runtime.h>
#include <math.h>

// MemoryUnit: fn=l2norm(feature), mn=l2norm(memory), S=fn.mn^T -> softmax ->
// hardshrink(0.0005) -> softmax -> w ; mem_feat = w @ memory.
// Round 3: prep builds Mem16[m][d] AND MemT[d][m] (tiled LDS transpose) so both
// GEMMs are identical m97-style kernels: global_load_lds width=16 staging into
// unpadded LDS with XOR-8 chunk swizzle, BM=256/BN=64/BK=64, split-K partials.

#define D_DIM 32768
#define B_DIM 256
#define M_DIM 2000
#define M_PAD 2048
#define NSPLIT 32
#define LAM 0.0005f

typedef __attribute__((ext_vector_type(8))) short bf16x8;   // 8 bf16 = 4 VGPR
typedef __attribute__((ext_vector_type(4))) float f32x4;

#define GLOBAL_AS __attribute__((address_space(1)))
#define LDS_AS __attribute__((address_space(3)))

__device__ __forceinline__ void cp_async16(const void* g, void* l) {
  // 64 lanes x 16B -> LDS base + lane*16 (wave-uniform lds base required)
  __builtin_amdgcn_global_load_lds((const GLOBAL_AS unsigned int*)g,
                                   (LDS_AS unsigned int*)l, 16, 0, 0);
}

__device__ __forceinline__ unsigned short f2bf(float f) {
  union { float f; unsigned u; } v; v.f = f;
  unsigned r = v.u + 0x7FFFu + ((v.u >> 16) & 1u);  // RNE
  return (unsigned short)(r >> 16);
}

// ---------------- zero (for rnm_sq atomics) ----------------
__global__ __launch_bounds__(256) void zero_kernel(float* __restrict__ p, int n) {
  int i = blockIdx.x * 256 + threadIdx.x;
  if (i < n) p[i] = 0.f;
}

// ---------------- prep feature: fp32 -> bf16 + 1/max(||x||,eps) ----------------
__global__ __launch_bounds__(256) void prep_feat_kernel(const float* __restrict__ src,
                                                        unsigned short* __restrict__ dst,
                                                        float* __restrict__ rn_inv) {
  const size_t row = blockIdx.x;
  const int t = threadIdx.x;
  const float4* p = (const float4*)(src + row * (size_t)D_DIM);
  ushort4* q = (ushort4*)(dst + row * (size_t)D_DIM);
  float s = 0.f;
  for (int i = t; i < D_DIM / 4; i += 256) {
    float4 v = p[i];
    s = fmaf(v.x, v.x, s); s = fmaf(v.y, v.y, s);
    s = fmaf(v.z, v.z, s); s = fmaf(v.w, v.w, s);
    ushort4 b; b.x = f2bf(v.x); b.y = f2bf(v.y); b.z = f2bf(v.z); b.w = f2bf(v.w);
    q[i] = b;
  }
  #pragma unroll
  for (int off = 32; off > 0; off >>= 1) s += __shfl_down(s, off, 64);
  __shared__ float partial[4];
  if ((t & 63) == 0) partial[t >> 6] = s;
  __syncthreads();
  if (t == 0) {
    float tt = partial[0] + partial[1] + partial[2] + partial[3];
    rn_inv[row] = 1.0f / fmaxf(sqrtf(tt), 1e-12f);
  }
}

// ---------------- prep memory: fp32[m][d] -> Mem16[m][d] + MemT[d][m] + sumsq ----
// Block = 64 m-rows x 256 d-cols (4 sub-tiles of 64x64 through LDS transpose).
#define LT_S 70   // LDS stride (ushorts): write 32-bank clean, transposed read 2-way
__global__ __launch_bounds__(256) void prep_mem_kernel(const float* __restrict__ src,
                                                       unsigned short* __restrict__ Mem16,
                                                       unsigned short* __restrict__ MemT,
                                                       float* __restrict__ rnm_sq) {
  __shared__ __align__(16) unsigned short LT[64 * LT_S];
  const int t = threadIdx.x;
  const int m0 = blockIdx.y * 64;
  const int d0 = blockIdx.x * 256;
  const int rrow = t >> 4;          // 0..15
  const int c4 = (t & 15) * 4;      // 0..60
  float nacc[4] = {0.f, 0.f, 0.f, 0.f};

  for (int sub = 0; sub < 4; sub++) {
    const int d = d0 + sub * 64;
    __syncthreads();                 // protect LT from previous sub-tile readers
    #pragma unroll
    for (int p = 0; p < 4; p++) {
      const int mr = rrow + 16 * p;  // 0..63
      const int m = m0 + mr;
      float4 v = make_float4(0.f, 0.f, 0.f, 0.f);
      if (m < M_DIM) v = *(const float4*)(src + (size_t)m * D_DIM + d + c4);
      nacc[p] = fmaf(v.x, v.x, fmaf(v.y, v.y, fmaf(v.z, v.z, fmaf(v.w, v.w, nacc[p]))));
      ushort4 b; b.x = f2bf(v.x); b.y = f2bf(v.y); b.z = f2bf(v.z); b.w = f2bf(v.w);
      *(ushort4*)&Mem16[(size_t)m * D_DIM + d + c4] = b;   // m>=2000 rows get zeros
      *(ushort4*)&LT[mr * LT_S + c4] = b;
    }
    __syncthreads();
    #pragma unroll
    for (int p = 0; p < 4; p++) {
      const int dl = rrow + 16 * p;  // 0..63
      ushort4 o;
      o.x = LT[(c4 + 0) * LT_S + dl];
      o.y = LT[(c4 + 1) * LT_S + dl];
      o.z = LT[(c4 + 2) * LT_S + dl];
      o.w = LT[(c4 + 3) * LT_S + dl];
      *(ushort4*)&MemT[(size_t)(d + dl) * M_PAD + m0 + c4] = o;
    }
  }
  // per-row sumsq: 16 lanes share a row; reduce then one atomic per row
  #pragma unroll
  for (int p = 0; p < 4; p++) {
    float s = nacc[p];
    #pragma unroll
    for (int off = 8; off > 0; off >>= 1) s += __shfl_down(s, off, 16);
    if ((t & 15) == 0) {
      const int m = m0 + rrow + 16 * p;
      if (m < M_DIM) atomicAdd(&rnm_sq[m], s);
    }
  }
}

// ---------------- shared GEMM core: D[mtile=256][ntile=64] += A . B^T over BK=64 ----
// A[m][k] k-contig (row stride lda), B[n][k] k-contig (row stride ldb).
// Staging: global_load_lds 16B, unpadded LDS (64 ushorts/row), XOR-8 chunk swizzle.
template <int KTILES>
__device__ __forceinline__ void gemm_core(const unsigned short* __restrict__ A,
                                          const unsigned short* __restrict__ B,
                                          size_t lda, size_t ldb,
                                          unsigned short* Asm, unsigned short* Bsm,
                                          f32x4 acc[4][4]) {
  const int t = threadIdx.x;
  const int wid = t >> 6, lane = t & 63;
  const int lr = lane & 15, kq = lane >> 4;
  const int l8 = lane & 7, lrow = lane >> 3;       // staging: 8 lanes x 16B per row
  const int sw_stage = (l8 ^ lrow) * 8;            // (r&7)==lrow for our row bases

  const unsigned short* Ab = A + (size_t)(64 * wid + lrow) * lda + sw_stage;
  const unsigned short* Bb = B + (size_t)(16 * wid + lrow) * ldb + sw_stage;

  for (int kt = 0; kt < KTILES; kt++) {
    const int kk = kt * 64;
    __syncthreads();                               // LDS free from previous iter
    #pragma unroll
    for (int i = 0; i < 8; i++)
      cp_async16(Ab + kk + (size_t)(8 * i) * lda, &Asm[(64 * wid + 8 * i) * 64]);
    #pragma unroll
    for (int i = 0; i < 2; i++)
      cp_async16(Bb + kk + (size_t)(8 * i) * ldb, &Bsm[(16 * wid + 8 * i) * 64]);
    __syncthreads();                               // vmcnt(0) drain before reads

    bf16x8 bfr[2][4];
    #pragma unroll
    for (int h = 0; h < 2; h++) {
      const int sw = ((h * 4 + kq) ^ (lr & 7)) * 8;
      #pragma unroll
      for (int ni = 0; ni < 4; ni++)
        bfr[h][ni] = *(const bf16x8*)&Bsm[(ni * 16 + lr) * 64 + sw];
    }
    #pragma unroll
    for (int mi = 0; mi < 4; mi++) {
      #pragma unroll
      for (int h = 0; h < 2; h++) {
        const int sw = ((h * 4 + kq) ^ (lr & 7)) * 8;
        const bf16x8 af = *(const bf16x8*)&Asm[(wid * 64 + mi * 16 + lr) * 64 + sw];
        #pragma unroll
        for (int ni = 0; ni < 4; ni++)
          acc[mi][ni] = __builtin_amdgcn_mfma_f32_16x16x32_bf16(af, bfr[h][ni], acc[mi][ni], 0, 0, 0);
      }
    }
  }
}

// ---------------- GEMM1: Spart[split][b][m] = F16 . Mem16^T over k-slab --------
__global__ __launch_bounds__(256) void gemm1_kernel(const unsigned short* __restrict__ A,
                                                    const unsigned short* __restrict__ Bm,
                                                    float* __restrict__ Spart) {
  __shared__ __align__(16) unsigned short Asm[256 * 64];  // 32 KB
  __shared__ __align__(16) unsigned short Bsm[64 * 64];   // 8 KB
  const int t = threadIdx.x;
  const int n0 = blockIdx.x * 64;
  const int kbase = blockIdx.y * (D_DIM / NSPLIT);
  const int wid = t >> 6, lane = t & 63;
  const int lr = lane & 15, kq = lane >> 4;

  f32x4 acc[4][4] = {};
  gemm_core<(D_DIM / NSPLIT) / 64>(A + kbase, Bm + (size_t)n0 * D_DIM + kbase,
                                   D_DIM, D_DIM, Asm, Bsm, acc);

  float* Sp = Spart + (size_t)blockIdx.y * (B_DIM * M_PAD);
  #pragma unroll
  for (int mi = 0; mi < 4; mi++) {
    const int row0 = wid * 64 + mi * 16 + kq * 4;
    #pragma unroll
    for (int ni = 0; ni < 4; ni++) {
      const int col = n0 + ni * 16 + lr;
      #pragma unroll
      for (int j = 0; j < 4; j++)
        Sp[(size_t)(row0 + j) * M_PAD + col] = acc[mi][ni][j];
    }
  }
}

// ---------------- GEMM2: C[b][n] = Wbf . MemT^T (K = M_PAD) ----------------
__global__ __launch_bounds__(256) void gemm2_kernel(const unsigned short* __restrict__ W,
                                                    const unsigned short* __restrict__ Bt,
                                                    float* __restrict__ C) {
  __shared__ __align__(16) unsigned short Asm[256 * 64];
  __shared__ __align__(16) unsigned short Bsm[64 * 64];
  const int t = threadIdx.x;
  const int n0 = blockIdx.x * 64;
  const int wid = t >> 6, lane = t & 63;
  const int lr = lane & 15, kq = lane >> 4;

  f32x4 acc[4][4] = {};
  gemm_core<M_PAD / 64>(W, Bt + (size_t)n0 * M_PAD, M_PAD, M_PAD, Asm, Bsm, acc);

  #pragma unroll
  for (int mi = 0; mi < 4; mi++) {
    const int row0 = wid * 64 + mi * 16 + kq * 4;
    #pragma unroll
    for (int ni = 0; ni < 4; ni++) {
      const int col = n0 + ni * 16 + lr;
      #pragma unroll
      for (int j = 0; j < 4; j++)
        C[(size_t)(row0 + j) * D_DIM + col] = acc[mi][ni][j];
    }
  }
}

// ---------------- softmax: reduce splits -> scale -> softmax -> shrink -> softmax ----
__device__ __forceinline__ float block_reduce(float x, bool is_max, float* red,
                                              int wid, int lane) {
  #pragma unroll
  for (int off = 32; off > 0; off >>= 1) {
    float o = __shfl_down(x, off, 64);
    x = is_max ? fmaxf(x, o) : (x + o);
  }
  __syncthreads();
  if (lane == 0) red[wid] = x;
  __syncthreads();
  return is_max ? fmaxf(fmaxf(red[0], red[1]), fmaxf(red[2], red[3]))
                : (red[0] + red[1] + red[2] + red[3]);
}

__global__ __launch_bounds__(256) void softmax_kernel(const float* __restrict__ Spart,
                                                      const float* __restrict__ rnf,
                                                      const float* __restrict__ rnm_sq,
                                                      float* __restrict__ wout,
                                                      unsigned short* __restrict__ wbf) {
  const int b = blockIdx.x;
  const int t = threadIdx.x;
  const int wid = t >> 6, lane = t & 63;
  const float sf = rnf[b];
  __shared__ float red[4];

  float v[8];
  #pragma unroll
  for (int i = 0; i < 8; i++) {
    const int m = t + 256 * i;
    float a = 0.f;
    #pragma unroll
    for (int s = 0; s < NSPLIT; s++)
      a += Spart[(size_t)s * (B_DIM * M_PAD) + (size_t)b * M_PAD + m];
    const float mscale = 1.0f / fmaxf(sqrtf(rnm_sq[m]), 1e-12f);
    v[i] = (m < M_DIM) ? a * (sf * mscale) : -INFINITY;
  }
  float mx = v[0];
  #pragma unroll
  for (int i = 1; i < 8; i++) mx = fmaxf(mx, v[i]);
  mx = block_reduce(mx, true, red, wid, lane);

  float e[8]; float sum = 0.f;
  #pragma unroll
  for (int i = 0; i < 8; i++) { e[i] = expf(v[i] - mx); sum += e[i]; }
  sum = block_reduce(sum, false, red, wid, lane);
  const float inv = 1.f / sum;

  float s2[8];
  #pragma unroll
  for (int i = 0; i < 8; i++) {
    float w1 = e[i] * inv;
    s2[i] = (w1 > LAM) ? w1 : 0.f;
  }
  float mx2 = 0.f;
  #pragma unroll
  for (int i = 0; i < 8; i++) mx2 = fmaxf(mx2, s2[i]);
  mx2 = block_reduce(mx2, true, red, wid, lane);

  float e2[8]; float sum2 = 0.f;
  #pragma unroll
  for (int i = 0; i < 8; i++) {
    const int m = t + 256 * i;
    e2[i] = (m < M_DIM) ? expf(s2[i] - mx2) : 0.f;
    sum2 += e2[i];
  }
  sum2 = block_reduce(sum2, false, red, wid, lane);
  const float inv2 = 1.f / sum2;

  #pragma unroll
  for (int i = 0; i < 8; i++) {
    const int m = t + 256 * i;
    const float w2 = e2[i] * inv2;
    if (m < M_DIM) wout[(size_t)b * M_DIM + m] = w2;
    wbf[(size_t)b * M_PAD + m] = f2bf(w2);   // padded cols exact 0
  }
}

// ---------------- launch ----------------
extern "C" void kernel_launch(void* const* d_in, const int* in_sizes, int n_in,
                              void* d_out, int out_size, void* d_ws, size_t ws_size,
                              hipStream_t stream) {
  const float* feature = (const float*)d_in[0];   // [256][32768]
  const float* memory  = (const float*)d_in[1];   // [2000][32768]
  float* out_feat = (float*)d_out;                         // [256][32768]
  float* out_w = out_feat + (size_t)B_DIM * D_DIM;         // [256][2000]

  char* ws = (char*)d_ws;
  unsigned short* Mem16 = (unsigned short*)ws;                       // [2048][32768] bf16
  unsigned short* MemT  = (unsigned short*)(ws + 134217728ull);      // [32768][2048] bf16
  unsigned short* F16   = (unsigned short*)(ws + 268435456ull);      // [256][32768] bf16
  unsigned short* Wbf   = (unsigned short*)(ws + 285212672ull);      // [256][2048] bf16
  float* Spart          = (float*)(ws + 286261248ull);               // [32][256][2048] fp32
  float* rnm_sq         = (float*)(ws + 353370112ull);               // [2048]
  float* rnf            = (float*)(ws + 353378304ull);               // [256]

  zero_kernel<<<(M_PAD + 255) / 256, 256, 0, stream>>>(rnm_sq, M_PAD);
  prep_feat_kernel<<<B_DIM, 256, 0, stream>>>(feature, F16, rnf);
  prep_mem_kernel<<<dim3(D_DIM / 256, 32), 256, 0, stream>>>(memory, Mem16, MemT, rnm_sq);
  gemm1_kernel<<<dim3(M_PAD / 64, NSPLIT), 256, 0, stream>>>(F16, Mem16, Spart);
  softmax_kernel<<<B_DIM, 256, 0, stream>>>(Spart, rnf, rnm_sq, out_w, Wbf);
  gemm2_kernel<<<D_DIM / 64, 256, 0, stream>>>(Wbf, MemT, out_feat);
}

// Round 4
// 519.929 us; speedup vs baseline: 1.1793x; 1.1793x over previous
//
#include <hip/hip_runtime.h>
#include <math.h>

// MemoryUnit: fn=l2norm(feature), mn=l2norm(memory), S=fn.mn^T -> softmax ->
// hardshrink(0.0005) -> softmax -> w ; mem_feat = w @ memory.
// Round 4: GEMM1 fused with memory prep (single fp32 pass over memory: cvt->LDS
// for MFMA B-operand, write Mem16 for GEMM2, sumsq for norms). GEMM2 stages W
// via global_load_lds (XOR-swizzled unpadded LDS) and transposes Mem16 tiles
// with register pair-packing + ds_write_b32 (conflict-free), frag ds_read_b128.

#define D_DIM 32768
#define B_DIM 256
#define M_DIM 2000
#define M_PAD 2048
#define NS1 16
#define KSLAB (D_DIM / NS1)   // 2048
#define LAM 0.0005f
#define LDB 72                // padded LDS stride (ushorts) for explicit-staged tiles

typedef __attribute__((ext_vector_type(8))) short bf16x8;   // 8 bf16 = 4 VGPR
typedef __attribute__((ext_vector_type(4))) float f32x4;

#define GLOBAL_AS __attribute__((address_space(1)))
#define LDS_AS __attribute__((address_space(3)))

__device__ __forceinline__ void cp_async16(const void* g, void* l) {
  // 64 lanes x 16B -> LDS base + lane*16 (wave-uniform lds base required)
  __builtin_amdgcn_global_load_lds((const GLOBAL_AS unsigned int*)g,
                                   (LDS_AS unsigned int*)l, 16, 0, 0);
}

__device__ __forceinline__ unsigned short f2bf(float f) {
  union { float f; unsigned u; } v; v.f = f;
  unsigned r = v.u + 0x7FFFu + ((v.u >> 16) & 1u);  // RNE
  return (unsigned short)(r >> 16);
}

// ---------------- zero (for rnm_sq atomics) ----------------
__global__ __launch_bounds__(256) void zero_kernel(float* __restrict__ p, int n) {
  int i = blockIdx.x * 256 + threadIdx.x;
  if (i < n) p[i] = 0.f;
}

// ---------------- prep feature: fp32 -> bf16 + 1/max(||x||,eps) ----------------
__global__ __launch_bounds__(256) void prep_feat_kernel(const float* __restrict__ src,
                                                        unsigned short* __restrict__ dst,
                                                        float* __restrict__ rn_inv) {
  const size_t row = blockIdx.x;
  const int t = threadIdx.x;
  const float4* p = (const float4*)(src + row * (size_t)D_DIM);
  ushort4* q = (ushort4*)(dst + row * (size_t)D_DIM);
  float s = 0.f;
  for (int i = t; i < D_DIM / 4; i += 256) {
    float4 v = p[i];
    s = fmaf(v.x, v.x, s); s = fmaf(v.y, v.y, s);
    s = fmaf(v.z, v.z, s); s = fmaf(v.w, v.w, s);
    ushort4 b; b.x = f2bf(v.x); b.y = f2bf(v.y); b.z = f2bf(v.z); b.w = f2bf(v.w);
    q[i] = b;
  }
  #pragma unroll
  for (int off = 32; off > 0; off >>= 1) s += __shfl_down(s, off, 64);
  __shared__ float partial[4];
  if ((t & 63) == 0) partial[t >> 6] = s;
  __syncthreads();
  if (t == 0) {
    float tt = partial[0] + partial[1] + partial[2] + partial[3];
    rn_inv[row] = 1.0f / fmaxf(sqrtf(tt), 1e-12f);
  }
}

// ---------------- fused GEMM1 + memory prep ----------------
// Grid (32 m-tiles, 16 k-splits). Block: 64 memory rows x 2048-k slab.
// Per BK=64 tile: A (F16 256x64) via cp_async16 into swizzled unpadded LDS;
// B: fp32 loads (256B/row granule) -> cvt bf16 -> padded LDS + Mem16 global write
// + sumsq accumulation. 32 MFMA/wave/tile. Epilogue: Spart stores + rnm atomics.
__global__ __launch_bounds__(256) void gemm1_fused(const unsigned short* __restrict__ F16,
                                                   const float* __restrict__ mem,
                                                   unsigned short* __restrict__ Mem16,
                                                   float* __restrict__ Spart,
                                                   float* __restrict__ rnm_sq) {
  __shared__ __align__(16) unsigned short Asm[256 * 64];   // 32 KB, swizzled
  __shared__ __align__(16) unsigned short Bsm[64 * LDB];   // 9 KB, padded
  const int t = threadIdx.x;
  const int m0 = blockIdx.x * 64;
  const int kbase = blockIdx.y * KSLAB;
  const int wid = t >> 6, lane = t & 63;
  const int lr = lane & 15, kq = lane >> 4;
  const int l8 = lane & 7, lrow = lane >> 3;

  // B staging: thread handles row (t>>2), 16 floats at col (t&3)*16
  const int brow = t >> 2;
  const int bcol = (t & 3) * 16;
  const int gm = m0 + brow;
  const bool bvalid = gm < M_DIM;
  const float* Bg = mem + (size_t)gm * D_DIM + kbase + bcol;
  unsigned short* M16g = Mem16 + (size_t)gm * D_DIM + kbase + bcol;

  const unsigned short* Ab = F16 + (size_t)(64 * wid + lrow) * D_DIM + kbase + (l8 ^ lrow) * 8;

  f32x4 acc[4][4] = {};
  float ss = 0.f;

  for (int kt = 0; kt < KSLAB / 64; kt++) {
    const int kk = kt * 64;
    __syncthreads();
    #pragma unroll
    for (int i = 0; i < 8; i++)
      cp_async16(Ab + kk + (size_t)(8 * i) * D_DIM, &Asm[(64 * wid + 8 * i) * 64]);

    // B: 4 float4 (64B) per thread, cvt, LDS + global bf16 store
    float4 v[4];
    #pragma unroll
    for (int j = 0; j < 4; j++)
      v[j] = bvalid ? *(const float4*)(Bg + kk + 4 * j) : make_float4(0.f, 0.f, 0.f, 0.f);
    ushort4 c[4];
    #pragma unroll
    for (int j = 0; j < 4; j++) {
      ss = fmaf(v[j].x, v[j].x, ss); ss = fmaf(v[j].y, v[j].y, ss);
      ss = fmaf(v[j].z, v[j].z, ss); ss = fmaf(v[j].w, v[j].w, ss);
      c[j].x = f2bf(v[j].x); c[j].y = f2bf(v[j].y);
      c[j].z = f2bf(v[j].z); c[j].w = f2bf(v[j].w);
    }
    *(ushort4*)&Bsm[brow * LDB + bcol + 0]  = c[0];
    *(ushort4*)&Bsm[brow * LDB + bcol + 4]  = c[1];
    *(ushort4*)&Bsm[brow * LDB + bcol + 8]  = c[2];
    *(ushort4*)&Bsm[brow * LDB + bcol + 12] = c[3];
    *(ushort4*)(M16g + kk + 0)  = c[0];
    *(ushort4*)(M16g + kk + 4)  = c[1];
    *(ushort4*)(M16g + kk + 8)  = c[2];
    *(ushort4*)(M16g + kk + 12) = c[3];
    __syncthreads();

    bf16x8 bfr[2][4];
    #pragma unroll
    for (int h = 0; h < 2; h++)
      #pragma unroll
      for (int ni = 0; ni < 4; ni++)
        bfr[h][ni] = *(const bf16x8*)&Bsm[(ni * 16 + lr) * LDB + h * 32 + kq * 8];
    #pragma unroll
    for (int mi = 0; mi < 4; mi++) {
      #pragma unroll
      for (int h = 0; h < 2; h++) {
        const int sw = ((h * 4 + kq) ^ (lr & 7)) * 8;
        const bf16x8 af = *(const bf16x8*)&Asm[(wid * 64 + mi * 16 + lr) * 64 + sw];
        #pragma unroll
        for (int ni = 0; ni < 4; ni++)
          acc[mi][ni] = __builtin_amdgcn_mfma_f32_16x16x32_bf16(af, bfr[h][ni], acc[mi][ni], 0, 0, 0);
      }
    }
  }

  // sumsq: 4 threads share a row (consecutive lanes)
  ss += __shfl_down(ss, 2, 4);
  ss += __shfl_down(ss, 1, 4);
  if ((t & 3) == 0 && bvalid) atomicAdd(&rnm_sq[gm], ss);

  // Spart[split][b][m]; C/D layout col=lane&15, row=(lane>>4)*4+j
  float* Sp = Spart + (size_t)blockIdx.y * (B_DIM * M_PAD);
  #pragma unroll
  for (int mi = 0; mi < 4; mi++) {
    const int b0 = wid * 64 + mi * 16 + kq * 4;
    #pragma unroll
    for (int ni = 0; ni < 4; ni++) {
      const int col = m0 + ni * 16 + lr;
      #pragma unroll
      for (int j = 0; j < 4; j++)
        Sp[(size_t)(b0 + j) * M_PAD + col] = acc[mi][ni][j];
    }
  }
}

// ---------------- softmax: reduce splits -> scale -> softmax -> shrink -> softmax ----
__device__ __forceinline__ float block_reduce(float x, bool is_max, float* red,
                                              int wid, int lane) {
  #pragma unroll
  for (int off = 32; off > 0; off >>= 1) {
    float o = __shfl_down(x, off, 64);
    x = is_max ? fmaxf(x, o) : (x + o);
  }
  __syncthreads();
  if (lane == 0) red[wid] = x;
  __syncthreads();
  return is_max ? fmaxf(fmaxf(red[0], red[1]), fmaxf(red[2], red[3]))
                : (red[0] + red[1] + red[2] + red[3]);
}

__global__ __launch_bounds__(256) void softmax_kernel(const float* __restrict__ Spart,
                                                      const float* __restrict__ rnf,
                                                      const float* __restrict__ rnm_sq,
                                                      float* __restrict__ wout,
                                                      unsigned short* __restrict__ wbf) {
  const int b = blockIdx.x;
  const int t = threadIdx.x;
  const int wid = t >> 6, lane = t & 63;
  const float sf = rnf[b];
  __shared__ float red[4];

  float v[8];
  #pragma unroll
  for (int i = 0; i < 8; i++) {
    const int m = t + 256 * i;
    float a = 0.f;
    #pragma unroll
    for (int s = 0; s < NS1; s++)
      a += Spart[(size_t)s * (B_DIM * M_PAD) + (size_t)b * M_PAD + m];
    const float mscale = 1.0f / fmaxf(sqrtf(rnm_sq[m]), 1e-12f);
    v[i] = (m < M_DIM) ? a * (sf * mscale) : -INFINITY;
  }
  float mx = v[0];
  #pragma unroll
  for (int i = 1; i < 8; i++) mx = fmaxf(mx, v[i]);
  mx = block_reduce(mx, true, red, wid, lane);

  float e[8]; float sum = 0.f;
  #pragma unroll
  for (int i = 0; i < 8; i++) { e[i] = expf(v[i] - mx); sum += e[i]; }
  sum = block_reduce(sum, false, red, wid, lane);
  const float inv = 1.f / sum;

  float s2[8];
  #pragma unroll
  for (int i = 0; i < 8; i++) {
    float w1 = e[i] * inv;
    s2[i] = (w1 > LAM) ? w1 : 0.f;
  }
  float mx2 = 0.f;
  #pragma unroll
  for (int i = 0; i < 8; i++) mx2 = fmaxf(mx2, s2[i]);
  mx2 = block_reduce(mx2, true, red, wid, lane);

  float e2[8]; float sum2 = 0.f;
  #pragma unroll
  for (int i = 0; i < 8; i++) {
    const int m = t + 256 * i;
    e2[i] = (m < M_DIM) ? expf(s2[i] - mx2) : 0.f;
    sum2 += e2[i];
  }
  sum2 = block_reduce(sum2, false, red, wid, lane);
  const float inv2 = 1.f / sum2;

  #pragma unroll
  for (int i = 0; i < 8; i++) {
    const int m = t + 256 * i;
    const float w2 = e2[i] * inv2;
    if (m < M_DIM) wout[(size_t)b * M_DIM + m] = w2;
    wbf[(size_t)b * M_PAD + m] = f2bf(w2);   // padded cols exact 0
  }
}

// ---------------- GEMM2: C[b][n] = sum_m Wbf[b][m] * Mem16[m][n] ----------------
// BM=256, BN=64, BK=64, 512 n-tiles. W via cp_async16 (swizzled); Mem16 tile
// transposed into Bt via register pair-pack + ds_write_b32 (bank spread full).
__global__ __launch_bounds__(256) void gemm2_kernel(const unsigned short* __restrict__ W,
                                                    const unsigned short* __restrict__ Bm,
                                                    float* __restrict__ C) {
  __shared__ __align__(16) unsigned short Wsm[256 * 64];   // 32 KB, swizzled
  __shared__ __align__(16) unsigned short Bt[64 * LDB];    // 9 KB, [n][k] padded
  const int t = threadIdx.x;
  const int n0 = blockIdx.x * 64;
  const int wid = t >> 6, lane = t & 63;
  const int lr = lane & 15, kq = lane >> 4;
  const int l8 = lane & 7, lrow = lane >> 3;

  const unsigned short* Wb = W + (size_t)(64 * wid + lrow) * M_PAD + (l8 ^ lrow) * 8;

  // Bt staging: thread handles k-pair kl2=2*(t>>4) (+32 on iter 2), 4 n at (t&15)*4
  const int kl2 = 2 * (t >> 4);
  const int d4 = (t & 15) * 4;

  f32x4 acc[4][4] = {};

  for (int k0 = 0; k0 < M_PAD; k0 += 64) {
    __syncthreads();
    #pragma unroll
    for (int i = 0; i < 8; i++)
      cp_async16(Wb + k0 + (size_t)(8 * i) * M_PAD, &Wsm[(64 * wid + 8 * i) * 64]);
    #pragma unroll
    for (int it = 0; it < 2; it++) {
      const int kl = kl2 + 32 * it;
      const ushort4 va = *(const ushort4*)(Bm + (size_t)(k0 + kl) * D_DIM + n0 + d4);
      const ushort4 vb = *(const ushort4*)(Bm + (size_t)(k0 + kl + 1) * D_DIM + n0 + d4);
      const unsigned p0 = (unsigned)va.x | ((unsigned)vb.x << 16);
      const unsigned p1 = (unsigned)va.y | ((unsigned)vb.y << 16);
      const unsigned p2 = (unsigned)va.z | ((unsigned)vb.z << 16);
      const unsigned p3 = (unsigned)va.w | ((unsigned)vb.w << 16);
      *(unsigned*)&Bt[(d4 + 0) * LDB + kl] = p0;
      *(unsigned*)&Bt[(d4 + 1) * LDB + kl] = p1;
      *(unsigned*)&Bt[(d4 + 2) * LDB + kl] = p2;
      *(unsigned*)&Bt[(d4 + 3) * LDB + kl] = p3;
    }
    __syncthreads();

    bf16x8 bfr[2][4];
    #pragma unroll
    for (int h = 0; h < 2; h++)
      #pragma unroll
      for (int ni = 0; ni < 4; ni++)
        bfr[h][ni] = *(const bf16x8*)&Bt[(ni * 16 + lr) * LDB + h * 32 + kq * 8];
    #pragma unroll
    for (int mi = 0; mi < 4; mi++) {
      #pragma unroll
      for (int h = 0; h < 2; h++) {
        const int sw = ((h * 4 + kq) ^ (lr & 7)) * 8;
        const bf16x8 af = *(const bf16x8*)&Wsm[(wid * 64 + mi * 16 + lr) * 64 + sw];
        #pragma unroll
        for (int ni = 0; ni < 4; ni++)
          acc[mi][ni] = __builtin_amdgcn_mfma_f32_16x16x32_bf16(af, bfr[h][ni], acc[mi][ni], 0, 0, 0);
      }
    }
  }
  #pragma unroll
  for (int mi = 0; mi < 4; mi++) {
    const int b0 = wid * 64 + mi * 16 + kq * 4;
    #pragma unroll
    for (int ni = 0; ni < 4; ni++) {
      const int col = n0 + ni * 16 + lr;
      #pragma unroll
      for (int j = 0; j < 4; j++)
        C[(size_t)(b0 + j) * D_DIM + col] = acc[mi][ni][j];
    }
  }
}

// ---------------- launch ----------------
extern "C" void kernel_launch(void* const* d_in, const int* in_sizes, int n_in,
                              void* d_out, int out_size, void* d_ws, size_t ws_size,
                              hipStream_t stream) {
  const float* feature = (const float*)d_in[0];   // [256][32768]
  const float* memory  = (const float*)d_in[1];   // [2000][32768]
  float* out_feat = (float*)d_out;                         // [256][32768]
  float* out_w = out_feat + (size_t)B_DIM * D_DIM;         // [256][2000]

  char* ws = (char*)d_ws;
  unsigned short* Mem16 = (unsigned short*)ws;                       // [2048][32768] bf16 (rows>=2000 zeroed)
  unsigned short* F16   = (unsigned short*)(ws + 134217728ull);      // [256][32768] bf16
  unsigned short* Wbf   = (unsigned short*)(ws + 150994944ull);      // [256][2048] bf16
  float* Spart          = (float*)(ws + 152043520ull);               // [16][256][2048] fp32
  float* rnm_sq         = (float*)(ws + 185597952ull);               // [2048]
  float* rnf            = (float*)(ws + 185606144ull);               // [256]

  zero_kernel<<<(M_PAD + 255) / 256, 256, 0, stream>>>(rnm_sq, M_PAD);
  prep_feat_kernel<<<B_DIM, 256, 0, stream>>>(feature, F16, rnf);
  gemm1_fused<<<dim3(M_PAD / 64, NS1), 256, 0, stream>>>(F16, memory, Mem16, Spart, rnm_sq);
  softmax_kernel<<<B_DIM, 256, 0, stream>>>(Spart, rnf, rnm_sq, out_w, Wbf);
  gemm2_kernel<<<D_DIM / 64, 256, 0, stream>>>(Wbf, Mem16, out_feat);
}

// Round 5
// 497.109 us; speedup vs baseline: 1.2334x; 1.0459x over previous
//
#include <hip/hip_runtime.h>
#include <math.h>

// MemoryUnit: fn=l2norm(feature), mn=l2norm(memory), S=fn.mn^T -> softmax ->
// hardshrink(0.0005) -> softmax -> w ; mem_feat = w @ memory.
// Round 5: no Mem16 materialization (write134+read134 == read262 twice).
// gemm1: fused memory-prep B-operand, no stores in loop. gemm2: fp32 memory
// direct, conflict-free swizzled LDS transpose staging. Both (256,3).

#define D_DIM 32768
#define B_DIM 256
#define M_DIM 2000
#define M_PAD 2048
#define NS1 16
#define KSLAB (D_DIM / NS1)   // 2048
#define LAM 0.0005f
#define LDB 72                // padded LDS stride (ushorts) for gemm1 B tile

typedef __attribute__((ext_vector_type(8))) short bf16x8;   // 8 bf16 = 4 VGPR
typedef __attribute__((ext_vector_type(4))) float f32x4;

#define GLOBAL_AS __attribute__((address_space(1)))
#define LDS_AS __attribute__((address_space(3)))

__device__ __forceinline__ void cp_async16(const void* g, void* l) {
  // 64 lanes x 16B -> LDS base + lane*16 (wave-uniform lds base required)
  __builtin_amdgcn_global_load_lds((const GLOBAL_AS unsigned int*)g,
                                   (LDS_AS unsigned int*)l, 16, 0, 0);
}

__device__ __forceinline__ unsigned short f2bf(float f) {
  union { float f; unsigned u; } v; v.f = f;
  unsigned r = v.u + 0x7FFFu + ((v.u >> 16) & 1u);  // RNE
  return (unsigned short)(r >> 16);
}

// ---------------- zero (for rnm_sq atomics) ----------------
__global__ __launch_bounds__(256) void zero_kernel(float* __restrict__ p, int n) {
  int i = blockIdx.x * 256 + threadIdx.x;
  if (i < n) p[i] = 0.f;
}

// ---------------- prep feature: fp32 -> bf16 + 1/max(||x||,eps) ----------------
__global__ __launch_bounds__(256) void prep_feat_kernel(const float* __restrict__ src,
                                                        unsigned short* __restrict__ dst,
                                                        float* __restrict__ rn_inv) {
  const size_t row = blockIdx.x;
  const int t = threadIdx.x;
  const float4* p = (const float4*)(src + row * (size_t)D_DIM);
  ushort4* q = (ushort4*)(dst + row * (size_t)D_DIM);
  float s = 0.f;
  for (int i = t; i < D_DIM / 4; i += 256) {
    float4 v = p[i];
    s = fmaf(v.x, v.x, s); s = fmaf(v.y, v.y, s);
    s = fmaf(v.z, v.z, s); s = fmaf(v.w, v.w, s);
    ushort4 b; b.x = f2bf(v.x); b.y = f2bf(v.y); b.z = f2bf(v.z); b.w = f2bf(v.w);
    q[i] = b;
  }
  #pragma unroll
  for (int off = 32; off > 0; off >>= 1) s += __shfl_down(s, off, 64);
  __shared__ float partial[4];
  if ((t & 63) == 0) partial[t >> 6] = s;
  __syncthreads();
  if (t == 0) {
    float tt = partial[0] + partial[1] + partial[2] + partial[3];
    rn_inv[row] = 1.0f / fmaxf(sqrtf(tt), 1e-12f);
  }
}

// ---------------- fused GEMM1 + memory norm ----------------
// Grid (32 m-tiles, 16 k-splits). A = F16 (cp_async16, swizzled unpadded LDS);
// B = memory fp32 -> cvt bf16 -> padded LDS; sumsq accumulated. No global stores
// in the K-loop. Epilogue: Spart + rnm_sq atomics.
__global__ __launch_bounds__(256, 3) void gemm1_fused(const unsigned short* __restrict__ F16,
                                                      const float* __restrict__ mem,
                                                      float* __restrict__ Spart,
                                                      float* __restrict__ rnm_sq) {
  __shared__ __align__(16) unsigned short Asm[256 * 64];   // 32 KB, swizzled
  __shared__ __align__(16) unsigned short Bsm[64 * LDB];   // 9 KB, padded
  const int t = threadIdx.x;
  const int m0 = blockIdx.x * 64;
  const int kbase = blockIdx.y * KSLAB;
  const int wid = t >> 6, lane = t & 63;
  const int lr = lane & 15, kq = lane >> 4;
  const int l8 = lane & 7, lrow = lane >> 3;

  // B staging: thread handles row (t>>2), 16 floats at col (t&3)*16
  const int brow = t >> 2;
  const int bcol = (t & 3) * 16;
  const int gm = m0 + brow;
  const bool bvalid = gm < M_DIM;
  const float* Bg = mem + (size_t)gm * D_DIM + kbase + bcol;

  const unsigned short* Ab = F16 + (size_t)(64 * wid + lrow) * D_DIM + kbase + (l8 ^ lrow) * 8;

  f32x4 acc[4][4] = {};
  float ss = 0.f;

  for (int kt = 0; kt < KSLAB / 64; kt++) {
    const int kk = kt * 64;
    __syncthreads();
    #pragma unroll
    for (int i = 0; i < 8; i++)
      cp_async16(Ab + kk + (size_t)(8 * i) * D_DIM, &Asm[(64 * wid + 8 * i) * 64]);

    float4 v[4];
    #pragma unroll
    for (int j = 0; j < 4; j++)
      v[j] = bvalid ? *(const float4*)(Bg + kk + 4 * j) : make_float4(0.f, 0.f, 0.f, 0.f);
    #pragma unroll
    for (int j = 0; j < 4; j++) {
      ss = fmaf(v[j].x, v[j].x, ss); ss = fmaf(v[j].y, v[j].y, ss);
      ss = fmaf(v[j].z, v[j].z, ss); ss = fmaf(v[j].w, v[j].w, ss);
      ushort4 c; c.x = f2bf(v[j].x); c.y = f2bf(v[j].y);
      c.z = f2bf(v[j].z); c.w = f2bf(v[j].w);
      *(ushort4*)&Bsm[brow * LDB + bcol + 4 * j] = c;
    }
    __syncthreads();

    bf16x8 bfr[2][4];
    #pragma unroll
    for (int h = 0; h < 2; h++)
      #pragma unroll
      for (int ni = 0; ni < 4; ni++)
        bfr[h][ni] = *(const bf16x8*)&Bsm[(ni * 16 + lr) * LDB + h * 32 + kq * 8];
    #pragma unroll
    for (int mi = 0; mi < 4; mi++) {
      #pragma unroll
      for (int h = 0; h < 2; h++) {
        const int sw = ((h * 4 + kq) ^ (lr & 7)) * 8;
        const bf16x8 af = *(const bf16x8*)&Asm[(wid * 64 + mi * 16 + lr) * 64 + sw];
        #pragma unroll
        for (int ni = 0; ni < 4; ni++)
          acc[mi][ni] = __builtin_amdgcn_mfma_f32_16x16x32_bf16(af, bfr[h][ni], acc[mi][ni], 0, 0, 0);
      }
    }
  }

  // sumsq: 4 threads share a row
  ss += __shfl_down(ss, 2, 4);
  ss += __shfl_down(ss, 1, 4);
  if ((t & 3) == 0 && bvalid) atomicAdd(&rnm_sq[gm], ss);

  // Spart[split][b][m]; C/D layout col=lane&15, row=(lane>>4)*4+j
  float* Sp = Spart + (size_t)blockIdx.y * (B_DIM * M_PAD);
  #pragma unroll
  for (int mi = 0; mi < 4; mi++) {
    const int b0 = wid * 64 + mi * 16 + kq * 4;
    #pragma unroll
    for (int ni = 0; ni < 4; ni++) {
      const int col = m0 + ni * 16 + lr;
      #pragma unroll
      for (int j = 0; j < 4; j++)
        Sp[(size_t)(b0 + j) * M_PAD + col] = acc[mi][ni][j];
    }
  }
}

// ---------------- softmax: reduce splits -> scale -> softmax -> shrink -> softmax ----
__device__ __forceinline__ float block_reduce(float x, bool is_max, float* red,
                                              int wid, int lane) {
  #pragma unroll
  for (int off = 32; off > 0; off >>= 1) {
    float o = __shfl_down(x, off, 64);
    x = is_max ? fmaxf(x, o) : (x + o);
  }
  __syncthreads();
  if (lane == 0) red[wid] = x;
  __syncthreads();
  return is_max ? fmaxf(fmaxf(red[0], red[1]), fmaxf(red[2], red[3]))
                : (red[0] + red[1] + red[2] + red[3]);
}

__global__ __launch_bounds__(256) void softmax_kernel(const float* __restrict__ Spart,
                                                      const float* __restrict__ rnf,
                                                      const float* __restrict__ rnm_sq,
                                                      float* __restrict__ wout,
                                                      unsigned short* __restrict__ wbf) {
  const int b = blockIdx.x;
  const int t = threadIdx.x;
  const int wid = t >> 6, lane = t & 63;
  const float sf = rnf[b];
  __shared__ float red[4];

  float v[8];
  #pragma unroll
  for (int g = 0; g < 2; g++) {
    const int mq = g * 1024 + 4 * t;             // quad base (quads never straddle M_DIM: 2000=4*500)
    f32x4 a = {0.f, 0.f, 0.f, 0.f};
    #pragma unroll
    for (int s = 0; s < NS1; s++)
      a += *(const f32x4*)&Spart[(size_t)s * (B_DIM * M_PAD) + (size_t)b * M_PAD + mq];
    #pragma unroll
    for (int j = 0; j < 4; j++) {
      const int m = mq + j;
      const float msc = 1.0f / fmaxf(sqrtf(rnm_sq[m]), 1e-12f);
      v[g * 4 + j] = (m < M_DIM) ? a[j] * (sf * msc) : -INFINITY;
    }
  }
  float mx = v[0];
  #pragma unroll
  for (int i = 1; i < 8; i++) mx = fmaxf(mx, v[i]);
  mx = block_reduce(mx, true, red, wid, lane);

  float e[8]; float sum = 0.f;
  #pragma unroll
  for (int i = 0; i < 8; i++) { e[i] = expf(v[i] - mx); sum += e[i]; }
  sum = block_reduce(sum, false, red, wid, lane);
  const float inv = 1.f / sum;

  float s2[8];
  #pragma unroll
  for (int i = 0; i < 8; i++) {
    float w1 = e[i] * inv;
    s2[i] = (w1 > LAM) ? w1 : 0.f;
  }
  float mx2 = 0.f;
  #pragma unroll
  for (int i = 0; i < 8; i++) mx2 = fmaxf(mx2, s2[i]);
  mx2 = block_reduce(mx2, true, red, wid, lane);

  float e2[8]; float sum2 = 0.f;
  #pragma unroll
  for (int g = 0; g < 2; g++)
    #pragma unroll
    for (int j = 0; j < 4; j++) {
      const int i = g * 4 + j;
      const int m = g * 1024 + 4 * t + j;
      e2[i] = (m < M_DIM) ? expf(s2[i] - mx2) : 0.f;
      sum2 += e2[i];
    }
  sum2 = block_reduce(sum2, false, red, wid, lane);
  const float inv2 = 1.f / sum2;

  #pragma unroll
  for (int g = 0; g < 2; g++) {
    const int mq = g * 1024 + 4 * t;
    float4 wq; ushort4 bq;
    float* wp = (float*)&wq;
    #pragma unroll
    for (int j = 0; j < 4; j++) {
      const float w2 = e2[g * 4 + j] * inv2;
      wp[j] = w2;
      ((unsigned short*)&bq)[j] = f2bf(w2);
    }
    if (mq + 3 < M_DIM) *(float4*)&wout[(size_t)b * M_DIM + mq] = wq;
    *(ushort4*)&wbf[(size_t)b * M_PAD + mq] = bq;   // padded cols exact 0
  }
}

// ---------------- GEMM2: C[b][n] = sum_k Wbf[b][k] * mem[k][n] (fp32 direct) ----
// BM=256, BN=64, BK=64, 512 n-tiles. W via cp_async16 (swizzled). B: thread owns
// col n=t&63, k-group kc=t>>6: 16 coalesced fp32 loads -> bf16 pack in regs ->
// 2 swizzled ds_write_b128 (8-lane cohorts cover all 32 banks: conflict-free).
__global__ __launch_bounds__(256, 3) void gemm2_kernel(const unsigned short* __restrict__ W,
                                                       const float* __restrict__ mem,
                                                       float* __restrict__ C) {
  __shared__ __align__(16) unsigned short Wsm[256 * 64];   // 32 KB, swizzled
  __shared__ __align__(16) unsigned short Bt[64 * 64];     // 8 KB, [n][k] swizzled
  const int t = threadIdx.x;
  const int n0 = blockIdx.x * 64;
  const int wid = t >> 6, lane = t & 63;
  const int lr = lane & 15, kq = lane >> 4;
  const int l8 = lane & 7, lrow = lane >> 3;

  const unsigned short* Wb = W + (size_t)(64 * wid + lrow) * M_PAD + (l8 ^ lrow) * 8;

  const int bn = t & 63;                 // column within n-tile
  const int kc = t >> 6;                 // 0..3 k-group (wave-uniform)
  const float* Bg = mem + (size_t)(kc * 16) * D_DIM + n0 + bn;

  f32x4 acc[4][4] = {};

  for (int k0 = 0; k0 < M_PAD; k0 += 64) {
    __syncthreads();
    #pragma unroll
    for (int i = 0; i < 8; i++)
      cp_async16(Wb + k0 + (size_t)(8 * i) * M_PAD, &Wsm[(64 * wid + 8 * i) * 64]);

    bf16x8 kb0, kb1;
    #pragma unroll
    for (int j = 0; j < 8; j++) {
      const int k = k0 + kc * 16 + j;    // wave-uniform predicate (kc uniform per wave)
      const float f = (k < M_DIM) ? Bg[(size_t)(k0 + j) * D_DIM] : 0.f;
      kb0[j] = (short)f2bf(f);
    }
    #pragma unroll
    for (int j = 8; j < 16; j++) {
      const int k = k0 + kc * 16 + j;
      const float f = (k < M_DIM) ? Bg[(size_t)(k0 + j) * D_DIM] : 0.f;
      kb1[j - 8] = (short)f2bf(f);
    }
    *(bf16x8*)&Bt[bn * 64 + (((kc * 2 + 0) ^ (bn & 7)) * 8)] = kb0;
    *(bf16x8*)&Bt[bn * 64 + (((kc * 2 + 1) ^ (bn & 7)) * 8)] = kb1;
    __syncthreads();

    bf16x8 bfr[2][4];
    #pragma unroll
    for (int h = 0; h < 2; h++)
      #pragma unroll
      for (int ni = 0; ni < 4; ni++)
        bfr[h][ni] = *(const bf16x8*)&Bt[(ni * 16 + lr) * 64 + (((h * 4 + kq) ^ (lr & 7)) * 8)];
    #pragma unroll
    for (int mi = 0; mi < 4; mi++) {
      #pragma unroll
      for (int h = 0; h < 2; h++) {
        const int sw = ((h * 4 + kq) ^ (lr & 7)) * 8;
        const bf16x8 af = *(const bf16x8*)&Wsm[(wid * 64 + mi * 16 + lr) * 64 + sw];
        #pragma unroll
        for (int ni = 0; ni < 4; ni++)
          acc[mi][ni] = __builtin_amdgcn_mfma_f32_16x16x32_bf16(af, bfr[h][ni], acc[mi][ni], 0, 0, 0);
      }
    }
  }
  #pragma unroll
  for (int mi = 0; mi < 4; mi++) {
    const int b0 = wid * 64 + mi * 16 + kq * 4;
    #pragma unroll
    for (int ni = 0; ni < 4; ni++) {
      const int col = n0 + ni * 16 + lr;
      #pragma unroll
      for (int j = 0; j < 4; j++)
        C[(size_t)(b0 + j) * D_DIM + col] = acc[mi][ni][j];
    }
  }
}

// ---------------- launch ----------------
extern "C" void kernel_launch(void* const* d_in, const int* in_sizes, int n_in,
                              void* d_out, int out_size, void* d_ws, size_t ws_size,
                              hipStream_t stream) {
  const float* feature = (const float*)d_in[0];   // [256][32768]
  const float* memory  = (const float*)d_in[1];   // [2000][32768]
  float* out_feat = (float*)d_out;                         // [256][32768]
  float* out_w = out_feat + (size_t)B_DIM * D_DIM;         // [256][2000]

  char* ws = (char*)d_ws;
  unsigned short* F16 = (unsigned short*)ws;                   // [256][32768] bf16 (16 MB)
  float* Spart        = (float*)(ws + 16777216ull);            // [16][256][2048] fp32 (33.5 MB)
  unsigned short* Wbf = (unsigned short*)(ws + 50331648ull);   // [256][2048] bf16 (1 MB)
  float* rnm_sq       = (float*)(ws + 51380224ull);            // [2048]
  float* rnf          = (float*)(ws + 51388416ull);            // [256]

  zero_kernel<<<(M_PAD + 255) / 256, 256, 0, stream>>>(rnm_sq, M_PAD);
  prep_feat_kernel<<<B_DIM, 256, 0, stream>>>(feature, F16, rnf);
  gemm1_fused<<<dim3(M_PAD / 64, NS1), 256, 0, stream>>>(F16, memory, Spart, rnm_sq);
  softmax_kernel<<<B_DIM, 256, 0, stream>>>(Spart, rnf, rnm_sq, out_w, Wbf);
  gemm2_kernel<<<D_DIM / 64, 256, 0, stream>>>(Wbf, memory, out_feat);
}